// Round 14
// baseline (368.744 us; speedup 1.0000x reference)
//
#include <hip/hip_runtime.h>
#include <hip/hip_bf16.h>

// Glm4MoeExpertLayers: x[T,H] fp32, Wgu[E,2I,H] fp32, Wdn[E,H,I] fp32, expert_idx
//   gu = x @ Wgu[e]^T ; hidden = silu(gu[:, :I]) * gu[:, I:] ; out = hidden @ Wdn[e]^T
// T=16384 H=2048 I=1536.
// R14: cut LDS bytes per MFMA (the measured binding resource).
//  GEMM1: 256Mx128N, 512thr/8 waves (4Mx2N), dual-B 4x4/wave. Staging B/MFMA
//          192->128, LDS 64KB (2 blk/CU -> 16 waves/CU).
//  GEMM2: 256Mx128N, 256thr/4 waves (2Mx2N), 8x4/wave. Frag B/MFMA 512->384,
//          staging 192->128, LDS 48KB.
// Proven conflict-free both-sides swizzle kept (slot ^= row&7 family, 0 conflicts
// since R10). Two-barrier loops (hand pipelines R4-R9 all null or worse).

namespace {

constexpr int T_ = 16384;
constexpr int H_ = 2048;
constexpr int I_ = 1536;

typedef short short8 __attribute__((ext_vector_type(8)));
typedef float f32x4 __attribute__((ext_vector_type(4)));
typedef unsigned short ushort4v __attribute__((ext_vector_type(4)));

__device__ __forceinline__ unsigned short f2bf(float f) {
    union { float f; unsigned u; } v; v.f = f;
    return (unsigned short)((v.u + 0x7FFFu + ((v.u >> 16) & 1u)) >> 16);
}

typedef __attribute__((address_space(1))) const void gvoid;
typedef __attribute__((address_space(3))) void lvoid;
__device__ __forceinline__ void gload16(const void* g, void* l) {
    __builtin_amdgcn_global_load_lds((gvoid*)g, (lvoid*)l, 16, 0, 0);
}

// ---------------------------------------------------------------------------
// fused fp32->bf16 conversion of x, Wgu[e], Wdn[e]
// ---------------------------------------------------------------------------
__global__ void k_cvt_all(const float* __restrict__ x, const float* __restrict__ wgu,
                          const float* __restrict__ wdn, const int* __restrict__ eidx,
                          unsigned short* __restrict__ xb, unsigned short* __restrict__ wgub,
                          unsigned short* __restrict__ wdnb) {
    const int e = *eidx;
    const int n1 = T_ * H_ / 4;
    const int n2 = 2 * I_ * H_ / 4;
    const int n3 = H_ * I_ / 4;
    const int ntot = n1 + n2 + n3;
    const float* wgu_e = wgu + (size_t)e * (size_t)(2 * I_) * H_;
    const float* wdn_e = wdn + (size_t)e * (size_t)H_ * I_;
    const int stride = gridDim.x * blockDim.x;
    for (int i = blockIdx.x * blockDim.x + threadIdx.x; i < ntot; i += stride) {
        const float* src; unsigned short* dst; int j;
        if (i < n1)           { src = x;     dst = xb;   j = i; }
        else if (i < n1 + n2) { src = wgu_e; dst = wgub; j = i - n1; }
        else                  { src = wdn_e; dst = wdnb; j = i - n1 - n2; }
        f32x4 v = ((const f32x4*)src)[j];
        ushort4v h = { f2bf(v[0]), f2bf(v[1]), f2bf(v[2]), f2bf(v[3]) };
        ((ushort4v*)dst)[j] = h;
    }
}

// ---------------------------------------------------------------------------
// GEMM1 + SwiGLU: hidden[T,I](bf16) = silu(xb@Wg^T) * (xb@Wu^T)
// 512 thr (8 waves 4Mx2N), tile 256Mx128N(hidden), BK=64 over H.
// LDS: A[256][64] 32K + Bg[128][64] 16K + Bu 16K = 64 KiB.
// ---------------------------------------------------------------------------
__global__ __launch_bounds__(512, 2) void k_gemm1_swiglu(
    const unsigned short* __restrict__ xb, const unsigned short* __restrict__ wgub,
    unsigned short* __restrict__ hidden)
{
    __shared__ unsigned short lds[32768];          // A 16384 | Bg 8192 | Bu 8192
    unsigned short* ldsA  = lds;
    unsigned short* ldsBg = lds + 16384;
    unsigned short* ldsBu = lds + 24576;

    const int tid  = threadIdx.x;
    const int lane = tid & 63;
    const int wid  = tid >> 6;     // 0..7
    const int wr   = wid >> 1;     // 0..3  M quarter
    const int wc   = wid & 1;      // 0..1  N half

    // XCD-aware bijective swizzle over 768 blocks (768 % 8 == 0)
    const int nb = (blockIdx.x & 7) * 96 + (blockIdx.x >> 3);
    const int bx = nb % 12, by = nb / 12;
    const int m0 = by * 256;
    const int n0 = bx * 128;

    f32x4 accG[4][4], accU[4][4];
    #pragma unroll
    for (int a = 0; a < 4; ++a)
        #pragma unroll
        for (int b = 0; b < 4; ++b) { accG[a][b] = (f32x4)0.0f; accU[a][b] = (f32x4)0.0f; }

    const int drow = lane >> 3;                   // 0..7 (== row & 7)
    const int gcol = (((lane & 7) ^ drow) * 8);   // pre-swizzled source col (bf16)
    const int l15 = lane & 15;
    const int l4  = lane >> 4;
    const int sw  = l15 & 7;

    for (int k0 = 0; k0 < H_; k0 += 64) {
        __syncthreads();
        // A: 256 rows (4 gloads/lane)
        #pragma unroll
        for (int r = 0; r < 4; ++r) {
            const int row  = r * 64 + wid * 8 + drow;
            const int loff = r * 4096 + wid * 512;
            gload16(xb + (size_t)(m0 + row) * H_ + k0 + gcol, ldsA + loff);
        }
        // Bg/Bu: 128 rows each (2+2 gloads/lane)
        #pragma unroll
        for (int r = 0; r < 2; ++r) {
            const int row  = r * 64 + wid * 8 + drow;
            const int loff = r * 4096 + wid * 512;
            gload16(wgub + (size_t)(n0 + row)      * H_ + k0 + gcol, ldsBg + loff);
            gload16(wgub + (size_t)(I_ + n0 + row) * H_ + k0 + gcol, ldsBu + loff);
        }
        __syncthreads();

        #pragma unroll
        for (int kk = 0; kk < 2; ++kk) {
            const int sl = ((kk * 4 + l4) ^ sw) * 8;
            short8 af[4], bg[4], bu[4];
            #pragma unroll
            for (int a = 0; a < 4; ++a) {
                const int r = wr * 64 + a * 16 + l15;
                af[a] = *(const short8*)(ldsA + r * 64 + sl);
            }
            #pragma unroll
            for (int b = 0; b < 4; ++b) {
                const int r = wc * 64 + b * 16 + l15;
                bg[b] = *(const short8*)(ldsBg + r * 64 + sl);
                bu[b] = *(const short8*)(ldsBu + r * 64 + sl);
            }
            #pragma unroll
            for (int a = 0; a < 4; ++a)
                #pragma unroll
                for (int b = 0; b < 4; ++b) {
                    accG[a][b] = __builtin_amdgcn_mfma_f32_16x16x32_bf16(af[a], bg[b], accG[a][b], 0, 0, 0);
                    accU[a][b] = __builtin_amdgcn_mfma_f32_16x16x32_bf16(af[a], bu[b], accU[a][b], 0, 0, 0);
                }
        }
    }

    // epilogue: silu(gate)*up -> bf16 hidden (in-wave)
    #pragma unroll
    for (int a = 0; a < 4; ++a)
        #pragma unroll
        for (int b = 0; b < 4; ++b)
            #pragma unroll
            for (int j = 0; j < 4; ++j) {
                const int row = m0 + wr * 64 + a * 16 + l4 * 4 + j;
                const int col = n0 + wc * 64 + b * 16 + l15;
                const float g = accG[a][b][j];
                const float u = accU[a][b][j];
                const float s = g / (1.0f + __expf(-g));
                hidden[(size_t)row * I_ + col] = f2bf(s * u);
            }
}

// ---------------------------------------------------------------------------
// GEMM2: out[T,H] fp32 = hidden(bf16) @ wdn_bf16^T.
// 256 thr (4 waves 2Mx2N), tile 256Mx128N, 8x4 frags/wave, BK=64 over I.
// LDS: A[256][64] 32K + B[128][64] 16K = 48 KiB.
// ---------------------------------------------------------------------------
__global__ __launch_bounds__(256, 2) void k_gemm2(
    const unsigned short* __restrict__ hidden, const unsigned short* __restrict__ wdnb,
    float* __restrict__ out)
{
    __shared__ unsigned short lds[24576];          // A 16384 | B 8192
    unsigned short* ldsA = lds;
    unsigned short* ldsB = lds + 16384;

    const int tid  = threadIdx.x;
    const int lane = tid & 63;
    const int wv   = tid >> 6;     // 0..3
    const int wr   = wv >> 1;      // 0..1  M half (128 rows each)
    const int wc   = wv & 1;       // 0..1  N half (64 cols each)

    // XCD swizzle over 1024 blocks (1024 % 8 == 0)
    const int nb = (blockIdx.x & 7) * 128 + (blockIdx.x >> 3);
    const int bx = nb % 16, by = nb / 16;
    const int m0 = by * 256;
    const int n0 = bx * 128;

    f32x4 acc[8][4];
    #pragma unroll
    for (int a = 0; a < 8; ++a)
        #pragma unroll
        for (int b = 0; b < 4; ++b) acc[a][b] = (f32x4)0.0f;

    const int drow = lane >> 3;
    const int gcol = (((lane & 7) ^ drow) * 8);
    const int l15 = lane & 15;
    const int l4  = lane >> 4;
    const int sw  = l15 & 7;

    for (int k0 = 0; k0 < I_; k0 += 64) {
        __syncthreads();
        // A: 256 rows (8 gloads/lane)
        #pragma unroll
        for (int r = 0; r < 8; ++r) {
            const int row  = r * 32 + wv * 8 + drow;
            const int loff = r * 2048 + wv * 512;
            gload16(hidden + (size_t)(m0 + row) * I_ + k0 + gcol, ldsA + loff);
        }
        // B: 128 rows (4 gloads/lane)
        #pragma unroll
        for (int r = 0; r < 4; ++r) {
            const int row  = r * 32 + wv * 8 + drow;
            const int loff = r * 2048 + wv * 512;
            gload16(wdnb + (size_t)(n0 + row) * I_ + k0 + gcol, ldsB + loff);
        }
        __syncthreads();

        #pragma unroll
        for (int kk = 0; kk < 2; ++kk) {
            const int sl = ((kk * 4 + l4) ^ sw) * 8;
            short8 af[8], bw[4];
            #pragma unroll
            for (int a = 0; a < 8; ++a) {
                const int r = wr * 128 + a * 16 + l15;
                af[a] = *(const short8*)(ldsA + r * 64 + sl);
            }
            #pragma unroll
            for (int b = 0; b < 4; ++b) {
                const int r = wc * 64 + b * 16 + l15;
                bw[b] = *(const short8*)(ldsB + r * 64 + sl);
            }
            #pragma unroll
            for (int a = 0; a < 8; ++a)
                #pragma unroll
                for (int b = 0; b < 4; ++b)
                    acc[a][b] = __builtin_amdgcn_mfma_f32_16x16x32_bf16(af[a], bw[b], acc[a][b], 0, 0, 0);
        }
    }

    #pragma unroll
    for (int a = 0; a < 8; ++a)
        #pragma unroll
        for (int b = 0; b < 4; ++b)
            #pragma unroll
            for (int j = 0; j < 4; ++j) {
                const int row = m0 + wr * 128 + a * 16 + l4 * 4 + j;
                const int col = n0 + wc * 64 + b * 16 + l15;
                out[(size_t)row * H_ + col] = acc[a][b][j];
            }
}

} // namespace

extern "C" void kernel_launch(void* const* d_in, const int* in_sizes, int n_in,
                              void* d_out, int out_size, void* d_ws, size_t ws_size,
                              hipStream_t stream) {
    const float* x   = (const float*)d_in[0];   // [T, H]
    const float* wgu = (const float*)d_in[1];   // [E, 2I, H]
    const float* wdn = (const float*)d_in[2];   // [E, H, I]
    const int* eidx  = (const int*)d_in[3];     // [1]
    float* out = (float*)d_out;                 // [T, H]

    // d_out (134.2 MB fp32) temporarily holds xb (67.1 MB) — dead before k_gemm2
    // overwrites it. ws: hidden | wgu_bf16 | wdn_bf16 = 69.2 MB.
    unsigned short* xb     = (unsigned short*)d_out;
    unsigned short* hidden = (unsigned short*)d_ws;
    unsigned short* wgub   = (unsigned short*)((char*)d_ws + 50331648);
    unsigned short* wdnb   = (unsigned short*)((char*)d_ws + 62914560);

    k_cvt_all<<<2048, 256, 0, stream>>>(x, wgu, wdn, eidx, xb, wgub, wdnb);
    k_gemm1_swiglu<<<dim3((T_ / 256) * (I_ / 128)), 512, 0, stream>>>(xb, wgub, hidden);
    k_gemm2<<<dim3((T_ / 256) * (H_ / 128)), 256, 0, stream>>>(hidden, wdnb, out);
}

// Round 15
// 324.194 us; speedup vs baseline: 1.1374x; 1.1374x over previous
//
#include <hip/hip_runtime.h>
#include <hip/hip_bf16.h>

// Glm4MoeExpertLayers: x[T,H] fp32, Wgu[E,2I,H] fp32, Wdn[E,H,I] fp32, expert_idx
//   gu = x @ Wgu[e]^T ; hidden = silu(gu[:, :I]) * gu[:, I:] ; out = hidden @ Wdn[e]^T
// T=16384 H=2048 I=1536.
// R15: consolidation of measured winners.
//  GEMM1 = R10-exact: 128x128, 4 waves 2x2, dual-B in-wave, BK=64, two-barrier
//          gload_lds, both-sides swizzle (slot ^= row&7) -> 0 conflicts, 190us.
//  GEMM2 = R14-exact: 256Mx128N, 4 waves 2Mx2N, 8x4 frags, BK=64, 48KB, ~89us.
//  cvt_all fused (HBM-bound, ~45us ~= floor).
// Laws learned: 4-wave blocks + small LDS + many blocks/CU beat every hand
// schedule (R4-R9 null, R8 spill disaster, R14 8-wave lockstep regression);
// swizzle must be both-sides via pre-swizzled global source (R9/R10).

namespace {

constexpr int T_ = 16384;
constexpr int H_ = 2048;
constexpr int I_ = 1536;

typedef short short8 __attribute__((ext_vector_type(8)));
typedef float f32x4 __attribute__((ext_vector_type(4)));
typedef unsigned short ushort4v __attribute__((ext_vector_type(4)));

__device__ __forceinline__ unsigned short f2bf(float f) {
    union { float f; unsigned u; } v; v.f = f;
    return (unsigned short)((v.u + 0x7FFFu + ((v.u >> 16) & 1u)) >> 16);
}

typedef __attribute__((address_space(1))) const void gvoid;
typedef __attribute__((address_space(3))) void lvoid;
__device__ __forceinline__ void gload16(const void* g, void* l) {
    __builtin_amdgcn_global_load_lds((gvoid*)g, (lvoid*)l, 16, 0, 0);
}

// ---------------------------------------------------------------------------
// fused fp32->bf16 conversion of x, Wgu[e], Wdn[e]
// ---------------------------------------------------------------------------
__global__ void k_cvt_all(const float* __restrict__ x, const float* __restrict__ wgu,
                          const float* __restrict__ wdn, const int* __restrict__ eidx,
                          unsigned short* __restrict__ xb, unsigned short* __restrict__ wgub,
                          unsigned short* __restrict__ wdnb) {
    const int e = *eidx;
    const int n1 = T_ * H_ / 4;
    const int n2 = 2 * I_ * H_ / 4;
    const int n3 = H_ * I_ / 4;
    const int ntot = n1 + n2 + n3;
    const float* wgu_e = wgu + (size_t)e * (size_t)(2 * I_) * H_;
    const float* wdn_e = wdn + (size_t)e * (size_t)H_ * I_;
    const int stride = gridDim.x * blockDim.x;
    for (int i = blockIdx.x * blockDim.x + threadIdx.x; i < ntot; i += stride) {
        const float* src; unsigned short* dst; int j;
        if (i < n1)           { src = x;     dst = xb;   j = i; }
        else if (i < n1 + n2) { src = wgu_e; dst = wgub; j = i - n1; }
        else                  { src = wdn_e; dst = wdnb; j = i - n1 - n2; }
        f32x4 v = ((const f32x4*)src)[j];
        ushort4v h = { f2bf(v[0]), f2bf(v[1]), f2bf(v[2]), f2bf(v[3]) };
        ((ushort4v*)dst)[j] = h;
    }
}

// ---------------------------------------------------------------------------
// GEMM1 + SwiGLU (R10-exact): hidden[T,I](bf16) = silu(xb@Wg^T) * (xb@Wu^T)
// 256 thr (4 waves 2x2), tile 128x128, BK=64 over H, dual-B in-wave.
// LDS 3 x [128 rows][8 slots 16B] = 48 KiB, slot ^= row&7 both-sides swizzle.
// ---------------------------------------------------------------------------
__global__ __launch_bounds__(256, 2) void k_gemm1_swiglu(
    const unsigned short* __restrict__ xb, const unsigned short* __restrict__ wgub,
    unsigned short* __restrict__ hidden)
{
    __shared__ unsigned short lds[3 * 128 * 64];
    unsigned short* ldsA  = lds;
    unsigned short* ldsBg = lds + 128 * 64;
    unsigned short* ldsBu = lds + 2 * 128 * 64;

    const int tid  = threadIdx.x;
    const int lane = tid & 63;
    const int wv   = tid >> 6;
    const int wr   = wv >> 1, wc = wv & 1;

    const int nb = (blockIdx.x & 7) * 192 + (blockIdx.x >> 3);
    const int bx = nb % 12, by = nb / 12;
    const int m0 = by * 128;
    const int n0 = bx * 128;

    f32x4 accG[4][4], accU[4][4];
    #pragma unroll
    for (int a = 0; a < 4; ++a)
        #pragma unroll
        for (int b = 0; b < 4; ++b) { accG[a][b] = (f32x4)0.0f; accU[a][b] = (f32x4)0.0f; }

    const int drow = lane >> 3;
    const int gcol = (((lane & 7) ^ drow) * 8);
    const int l15 = lane & 15;
    const int l4  = lane >> 4;
    const int sw  = l15 & 7;

    for (int k0 = 0; k0 < H_; k0 += 64) {
        __syncthreads();
        #pragma unroll
        for (int r = 0; r < 4; ++r) {
            const int row  = r * 32 + wv * 8 + drow;
            const int loff = r * 2048 + wv * 512;
            gload16(xb   + (size_t)(m0 + row)      * H_ + k0 + gcol, ldsA  + loff);
            gload16(wgub + (size_t)(n0 + row)      * H_ + k0 + gcol, ldsBg + loff);
            gload16(wgub + (size_t)(I_ + n0 + row) * H_ + k0 + gcol, ldsBu + loff);
        }
        __syncthreads();

        #pragma unroll
        for (int kk = 0; kk < 2; ++kk) {
            const int sl = ((kk * 4 + l4) ^ sw) * 8;
            short8 af[4], bg[4], bu[4];
            #pragma unroll
            for (int a = 0; a < 4; ++a) {
                const int r = wr * 64 + a * 16 + l15;
                af[a] = *(const short8*)(ldsA + r * 64 + sl);
            }
            #pragma unroll
            for (int b = 0; b < 4; ++b) {
                const int r = wc * 64 + b * 16 + l15;
                bg[b] = *(const short8*)(ldsBg + r * 64 + sl);
                bu[b] = *(const short8*)(ldsBu + r * 64 + sl);
            }
            #pragma unroll
            for (int a = 0; a < 4; ++a)
                #pragma unroll
                for (int b = 0; b < 4; ++b) {
                    accG[a][b] = __builtin_amdgcn_mfma_f32_16x16x32_bf16(af[a], bg[b], accG[a][b], 0, 0, 0);
                    accU[a][b] = __builtin_amdgcn_mfma_f32_16x16x32_bf16(af[a], bu[b], accU[a][b], 0, 0, 0);
                }
        }
    }

    #pragma unroll
    for (int a = 0; a < 4; ++a)
        #pragma unroll
        for (int b = 0; b < 4; ++b)
            #pragma unroll
            for (int j = 0; j < 4; ++j) {
                const int row = m0 + wr * 64 + a * 16 + l4 * 4 + j;
                const int col = n0 + wc * 64 + b * 16 + l15;
                const float g = accG[a][b][j];
                const float u = accU[a][b][j];
                const float s = g / (1.0f + __expf(-g));
                hidden[(size_t)row * I_ + col] = f2bf(s * u);
            }
}

// ---------------------------------------------------------------------------
// GEMM2 (R14-exact): out[T,H] fp32 = hidden(bf16) @ wdn_bf16^T.
// 256 thr (4 waves 2Mx2N), tile 256Mx128N, 8x4 frags/wave, BK=64 over I.
// LDS: A[256][64] 32K + B[128][64] 16K = 48 KiB.
// ---------------------------------------------------------------------------
__global__ __launch_bounds__(256, 2) void k_gemm2(
    const unsigned short* __restrict__ hidden, const unsigned short* __restrict__ wdnb,
    float* __restrict__ out)
{
    __shared__ unsigned short lds[24576];
    unsigned short* ldsA = lds;
    unsigned short* ldsB = lds + 16384;

    const int tid  = threadIdx.x;
    const int lane = tid & 63;
    const int wv   = tid >> 6;
    const int wr   = wv >> 1;
    const int wc   = wv & 1;

    const int nb = (blockIdx.x & 7) * 128 + (blockIdx.x >> 3);
    const int bx = nb % 16, by = nb / 16;
    const int m0 = by * 256;
    const int n0 = bx * 128;

    f32x4 acc[8][4];
    #pragma unroll
    for (int a = 0; a < 8; ++a)
        #pragma unroll
        for (int b = 0; b < 4; ++b) acc[a][b] = (f32x4)0.0f;

    const int drow = lane >> 3;
    const int gcol = (((lane & 7) ^ drow) * 8);
    const int l15 = lane & 15;
    const int l4  = lane >> 4;
    const int sw  = l15 & 7;

    for (int k0 = 0; k0 < I_; k0 += 64) {
        __syncthreads();
        #pragma unroll
        for (int r = 0; r < 8; ++r) {
            const int row  = r * 32 + wv * 8 + drow;
            const int loff = r * 2048 + wv * 512;
            gload16(hidden + (size_t)(m0 + row) * I_ + k0 + gcol, ldsA + loff);
        }
        #pragma unroll
        for (int r = 0; r < 4; ++r) {
            const int row  = r * 32 + wv * 8 + drow;
            const int loff = r * 2048 + wv * 512;
            gload16(wdnb + (size_t)(n0 + row) * I_ + k0 + gcol, ldsB + loff);
        }
        __syncthreads();

        #pragma unroll
        for (int kk = 0; kk < 2; ++kk) {
            const int sl = ((kk * 4 + l4) ^ sw) * 8;
            short8 af[8], bw[4];
            #pragma unroll
            for (int a = 0; a < 8; ++a) {
                const int r = wr * 128 + a * 16 + l15;
                af[a] = *(const short8*)(ldsA + r * 64 + sl);
            }
            #pragma unroll
            for (int b = 0; b < 4; ++b) {
                const int r = wc * 64 + b * 16 + l15;
                bw[b] = *(const short8*)(ldsB + r * 64 + sl);
            }
            #pragma unroll
            for (int a = 0; a < 8; ++a)
                #pragma unroll
                for (int b = 0; b < 4; ++b)
                    acc[a][b] = __builtin_amdgcn_mfma_f32_16x16x32_bf16(af[a], bw[b], acc[a][b], 0, 0, 0);
        }
    }

    #pragma unroll
    for (int a = 0; a < 8; ++a)
        #pragma unroll
        for (int b = 0; b < 4; ++b)
            #pragma unroll
            for (int j = 0; j < 4; ++j) {
                const int row = m0 + wr * 128 + a * 16 + l4 * 4 + j;
                const int col = n0 + wc * 64 + b * 16 + l15;
                out[(size_t)row * H_ + col] = acc[a][b][j];
            }
}

} // namespace

extern "C" void kernel_launch(void* const* d_in, const int* in_sizes, int n_in,
                              void* d_out, int out_size, void* d_ws, size_t ws_size,
                              hipStream_t stream) {
    const float* x   = (const float*)d_in[0];   // [T, H]
    const float* wgu = (const float*)d_in[1];   // [E, 2I, H]
    const float* wdn = (const float*)d_in[2];   // [E, H, I]
    const int* eidx  = (const int*)d_in[3];     // [1]
    float* out = (float*)d_out;                 // [T, H]

    // d_out (134.2 MB fp32) temporarily holds xb (67.1 MB) — dead before k_gemm2
    // overwrites it. ws: hidden | wgu_bf16 | wdn_bf16 = 69.2 MB.
    unsigned short* xb     = (unsigned short*)d_out;
    unsigned short* hidden = (unsigned short*)d_ws;
    unsigned short* wgub   = (unsigned short*)((char*)d_ws + 50331648);
    unsigned short* wdnb   = (unsigned short*)((char*)d_ws + 62914560);

    k_cvt_all<<<2048, 256, 0, stream>>>(x, wgu, wdn, eidx, xb, wgub, wdnb);
    k_gemm1_swiglu<<<dim3((I_ / 128) * (T_ / 128)), 256, 0, stream>>>(xb, wgub, hidden);
    k_gemm2<<<dim3((T_ / 256) * (H_ / 128)), 256, 0, stream>>>(hidden, wdnb, out);
}

// Round 16
// 319.370 us; speedup vs baseline: 1.1546x; 1.0151x over previous
//
#include <hip/hip_runtime.h>
#include <hip/hip_bf16.h>

// Glm4MoeExpertLayers: x[T,H] fp32, Wgu[E,2I,H] fp32, Wdn[E,H,I] fp32, expert_idx
//   gu = x @ Wgu[e]^T ; hidden = silu(gu[:, :I]) * gu[:, I:] ; out = hidden @ Wdn[e]^T
// T=16384 H=2048 I=1536.
// R16 = R15 winners + surgical A-double-buffer with counted vmcnt:
//   stage B(t) ; stage A(t+1) ; s_waitcnt vmcnt(#A-loads) ; s_barrier ;
//   compute(t) ; s_barrier.
// A(t+1)'s DMA flies through the whole compute window (counted wait never
// drains it); exposed stage window shrinks 12->8 loads (G1), 12->4 (G2).
// GEMM1: A dbuf 2x16K + Bg 16K + Bu 16K = 64KB (2 blk/CU).
// GEMM2: A dbuf 2x32K + B 16K = 80KB (2 blk/CU).
// Proven conflict-free both-sides swizzle kept (0 conflicts since R10).

namespace {

constexpr int T_ = 16384;
constexpr int H_ = 2048;
constexpr int I_ = 1536;

typedef short short8 __attribute__((ext_vector_type(8)));
typedef float f32x4 __attribute__((ext_vector_type(4)));
typedef unsigned short ushort4v __attribute__((ext_vector_type(4)));

__device__ __forceinline__ unsigned short f2bf(float f) {
    union { float f; unsigned u; } v; v.f = f;
    return (unsigned short)((v.u + 0x7FFFu + ((v.u >> 16) & 1u)) >> 16);
}

typedef __attribute__((address_space(1))) const void gvoid;
typedef __attribute__((address_space(3))) void lvoid;
__device__ __forceinline__ void gload16(const void* g, void* l) {
    __builtin_amdgcn_global_load_lds((gvoid*)g, (lvoid*)l, 16, 0, 0);
}

#define SBAR() do { __builtin_amdgcn_s_barrier(); __builtin_amdgcn_sched_barrier(0); } while (0)
#define VMW(n) do { asm volatile("s_waitcnt vmcnt(" #n ")" ::: "memory"); __builtin_amdgcn_sched_barrier(0); } while (0)

// ---------------------------------------------------------------------------
// fused fp32->bf16 conversion of x, Wgu[e], Wdn[e]
// ---------------------------------------------------------------------------
__global__ void k_cvt_all(const float* __restrict__ x, const float* __restrict__ wgu,
                          const float* __restrict__ wdn, const int* __restrict__ eidx,
                          unsigned short* __restrict__ xb, unsigned short* __restrict__ wgub,
                          unsigned short* __restrict__ wdnb) {
    const int e = *eidx;
    const int n1 = T_ * H_ / 4;
    const int n2 = 2 * I_ * H_ / 4;
    const int n3 = H_ * I_ / 4;
    const int ntot = n1 + n2 + n3;
    const float* wgu_e = wgu + (size_t)e * (size_t)(2 * I_) * H_;
    const float* wdn_e = wdn + (size_t)e * (size_t)H_ * I_;
    const int stride = gridDim.x * blockDim.x;
    for (int i = blockIdx.x * blockDim.x + threadIdx.x; i < ntot; i += stride) {
        const float* src; unsigned short* dst; int j;
        if (i < n1)           { src = x;     dst = xb;   j = i; }
        else if (i < n1 + n2) { src = wgu_e; dst = wgub; j = i - n1; }
        else                  { src = wdn_e; dst = wdnb; j = i - n1 - n2; }
        f32x4 v = ((const f32x4*)src)[j];
        ushort4v h = { f2bf(v[0]), f2bf(v[1]), f2bf(v[2]), f2bf(v[3]) };
        ((ushort4v*)dst)[j] = h;
    }
}

// ---------------------------------------------------------------------------
// GEMM1 + SwiGLU: hidden[T,I](bf16) = silu(xb@Wg^T) * (xb@Wu^T)
// 256 thr (4 waves 2x2), tile 128x128, BK=64 over H, dual-B in-wave.
// A double-buffered (counted vmcnt(4)); Bg/Bu staged in exposed window.
// ---------------------------------------------------------------------------
__global__ __launch_bounds__(256, 2) void k_gemm1_swiglu(
    const unsigned short* __restrict__ xb, const unsigned short* __restrict__ wgub,
    unsigned short* __restrict__ hidden)
{
    __shared__ unsigned short lds[4 * 8192];   // A0 | A1 | Bg | Bu (each 16 KiB)
    unsigned short* ldsBg = lds + 16384;
    unsigned short* ldsBu = lds + 24576;

    const int tid  = threadIdx.x;
    const int lane = tid & 63;
    const int wv   = tid >> 6;
    const int wr   = wv >> 1, wc = wv & 1;

    const int nb = (blockIdx.x & 7) * 192 + (blockIdx.x >> 3);
    const int bx = nb % 12, by = nb / 12;
    const int m0 = by * 128;
    const int n0 = bx * 128;

    f32x4 accG[4][4], accU[4][4];
    #pragma unroll
    for (int a = 0; a < 4; ++a)
        #pragma unroll
        for (int b = 0; b < 4; ++b) { accG[a][b] = (f32x4)0.0f; accU[a][b] = (f32x4)0.0f; }

    const int drow = lane >> 3;
    const int gcol = (((lane & 7) ^ drow) * 8);
    const int l15 = lane & 15;
    const int l4  = lane >> 4;
    const int sw  = l15 & 7;

    constexpr int NT = H_ / 64;   // 32

    auto stageA = [&](int t) {
        unsigned short* dA = lds + (t & 1) * 8192;
        const int kS = t * 64;
        #pragma unroll
        for (int r = 0; r < 4; ++r) {
            const int row  = r * 32 + wv * 8 + drow;
            const int loff = r * 2048 + wv * 512;
            gload16(xb + (size_t)(m0 + row) * H_ + kS + gcol, dA + loff);
        }
    };
    auto stageB = [&](int t) {
        const int kS = t * 64;
        #pragma unroll
        for (int r = 0; r < 4; ++r) {
            const int row  = r * 32 + wv * 8 + drow;
            const int loff = r * 2048 + wv * 512;
            gload16(wgub + (size_t)(n0 + row)      * H_ + kS + gcol, ldsBg + loff);
            gload16(wgub + (size_t)(I_ + n0 + row) * H_ + kS + gcol, ldsBu + loff);
        }
    };

    stageA(0);   // 4 loads in flight

    for (int t = 0; t < NT; ++t) {
        stageB(t);                         // 8 loads (exposed window)
        if (t + 1 < NT) { stageA(t + 1); VMW(4); }   // A(t+1) stays in flight
        else            { VMW(0); }
        SBAR();

        const unsigned short* bA = lds + (t & 1) * 8192;
        #pragma unroll
        for (int kk = 0; kk < 2; ++kk) {
            const int sl = ((kk * 4 + l4) ^ sw) * 8;
            short8 af[4], bg[4], bu[4];
            #pragma unroll
            for (int a = 0; a < 4; ++a) {
                const int r = wr * 64 + a * 16 + l15;
                af[a] = *(const short8*)(bA + r * 64 + sl);
            }
            #pragma unroll
            for (int b = 0; b < 4; ++b) {
                const int r = wc * 64 + b * 16 + l15;
                bg[b] = *(const short8*)(ldsBg + r * 64 + sl);
                bu[b] = *(const short8*)(ldsBu + r * 64 + sl);
            }
            #pragma unroll
            for (int a = 0; a < 4; ++a)
                #pragma unroll
                for (int b = 0; b < 4; ++b) {
                    accG[a][b] = __builtin_amdgcn_mfma_f32_16x16x32_bf16(af[a], bg[b], accG[a][b], 0, 0, 0);
                    accU[a][b] = __builtin_amdgcn_mfma_f32_16x16x32_bf16(af[a], bu[b], accU[a][b], 0, 0, 0);
                }
        }
        SBAR();   // all waves done reading Bg/Bu and bufA[t&1]
    }

    #pragma unroll
    for (int a = 0; a < 4; ++a)
        #pragma unroll
        for (int b = 0; b < 4; ++b)
            #pragma unroll
            for (int j = 0; j < 4; ++j) {
                const int row = m0 + wr * 64 + a * 16 + l4 * 4 + j;
                const int col = n0 + wc * 64 + b * 16 + l15;
                const float g = accG[a][b][j];
                const float u = accU[a][b][j];
                const float s = g / (1.0f + __expf(-g));
                hidden[(size_t)row * I_ + col] = f2bf(s * u);
            }
}

// ---------------------------------------------------------------------------
// GEMM2: out[T,H] fp32 = hidden(bf16) @ wdn_bf16^T.
// 256 thr (4 waves 2Mx2N), tile 256Mx128N, 8x4 frags/wave, BK=64 over I.
// A double-buffered (counted vmcnt(8)); B staged in exposed window (4 loads).
// ---------------------------------------------------------------------------
__global__ __launch_bounds__(256, 2) void k_gemm2(
    const unsigned short* __restrict__ hidden, const unsigned short* __restrict__ wdnb,
    float* __restrict__ out)
{
    __shared__ unsigned short lds[2 * 16384 + 8192];   // A0 | A1 (32K each) | B 16K
    unsigned short* ldsB = lds + 32768;

    const int tid  = threadIdx.x;
    const int lane = tid & 63;
    const int wv   = tid >> 6;
    const int wr   = wv >> 1;
    const int wc   = wv & 1;

    const int nb = (blockIdx.x & 7) * 128 + (blockIdx.x >> 3);
    const int bx = nb % 16, by = nb / 16;
    const int m0 = by * 256;
    const int n0 = bx * 128;

    f32x4 acc[8][4];
    #pragma unroll
    for (int a = 0; a < 8; ++a)
        #pragma unroll
        for (int b = 0; b < 4; ++b) acc[a][b] = (f32x4)0.0f;

    const int drow = lane >> 3;
    const int gcol = (((lane & 7) ^ drow) * 8);
    const int l15 = lane & 15;
    const int l4  = lane >> 4;
    const int sw  = l15 & 7;

    constexpr int NT = I_ / 64;   // 24

    auto stageA = [&](int t) {
        unsigned short* dA = lds + (t & 1) * 16384;
        const int kS = t * 64;
        #pragma unroll
        for (int r = 0; r < 8; ++r) {
            const int row  = r * 32 + wv * 8 + drow;
            const int loff = r * 2048 + wv * 512;
            gload16(hidden + (size_t)(m0 + row) * I_ + kS + gcol, dA + loff);
        }
    };
    auto stageB = [&](int t) {
        const int kS = t * 64;
        #pragma unroll
        for (int r = 0; r < 4; ++r) {
            const int row  = r * 32 + wv * 8 + drow;
            const int loff = r * 2048 + wv * 512;
            gload16(wdnb + (size_t)(n0 + row) * I_ + kS + gcol, ldsB + loff);
        }
    };

    stageA(0);   // 8 loads in flight

    for (int t = 0; t < NT; ++t) {
        stageB(t);                          // 4 loads (exposed window)
        if (t + 1 < NT) { stageA(t + 1); VMW(8); }
        else            { VMW(0); }
        SBAR();

        const unsigned short* bA = lds + (t & 1) * 16384;
        #pragma unroll
        for (int kk = 0; kk < 2; ++kk) {
            const int sl = ((kk * 4 + l4) ^ sw) * 8;
            short8 af[8], bw[4];
            #pragma unroll
            for (int a = 0; a < 8; ++a) {
                const int r = wr * 128 + a * 16 + l15;
                af[a] = *(const short8*)(bA + r * 64 + sl);
            }
            #pragma unroll
            for (int b = 0; b < 4; ++b) {
                const int r = wc * 64 + b * 16 + l15;
                bw[b] = *(const short8*)(ldsB + r * 64 + sl);
            }
            #pragma unroll
            for (int a = 0; a < 8; ++a)
                #pragma unroll
                for (int b = 0; b < 4; ++b)
                    acc[a][b] = __builtin_amdgcn_mfma_f32_16x16x32_bf16(af[a], bw[b], acc[a][b], 0, 0, 0);
        }
        SBAR();
    }

    #pragma unroll
    for (int a = 0; a < 8; ++a)
        #pragma unroll
        for (int b = 0; b < 4; ++b)
            #pragma unroll
            for (int j = 0; j < 4; ++j) {
                const int row = m0 + wr * 128 + a * 16 + l4 * 4 + j;
                const int col = n0 + wc * 64 + b * 16 + l15;
                out[(size_t)row * H_ + col] = acc[a][b][j];
            }
}

} // namespace

extern "C" void kernel_launch(void* const* d_in, const int* in_sizes, int n_in,
                              void* d_out, int out_size, void* d_ws, size_t ws_size,
                              hipStream_t stream) {
    const float* x   = (const float*)d_in[0];   // [T, H]
    const float* wgu = (const float*)d_in[1];   // [E, 2I, H]
    const float* wdn = (const float*)d_in[2];   // [E, H, I]
    const int* eidx  = (const int*)d_in[3];     // [1]
    float* out = (float*)d_out;                 // [T, H]

    // d_out (134.2 MB fp32) temporarily holds xb (67.1 MB) — dead before k_gemm2
    // overwrites it. ws: hidden | wgu_bf16 | wdn_bf16 = 69.2 MB.
    unsigned short* xb     = (unsigned short*)d_out;
    unsigned short* hidden = (unsigned short*)d_ws;
    unsigned short* wgub   = (unsigned short*)((char*)d_ws + 50331648);
    unsigned short* wdnb   = (unsigned short*)((char*)d_ws + 62914560);

    k_cvt_all<<<2048, 256, 0, stream>>>(x, wgu, wdn, eidx, xb, wgub, wdnb);
    k_gemm1_swiglu<<<dim3((I_ / 128) * (T_ / 128)), 256, 0, stream>>>(xb, wgub, hidden);
    k_gemm2<<<dim3((T_ / 256) * (H_ / 128)), 256, 0, stream>>>(hidden, wdnb, out);
}